// Round 1
// baseline (295.381 us; speedup 1.0000x reference)
//
#include <hip/hip_runtime.h>
#include <stdint.h>

#define B_ 2
#define S_ 2048
#define D_ 1024
#define H_ 16
#define C_ 64
#define M_ (B_*S_)     // 4096 tokens
#define N1_ (3*D_)     // 3072 qkv cols

typedef float f32x4 __attribute__((ext_vector_type(4)));
typedef __bf16 bf16x8 __attribute__((ext_vector_type(8)));

static __device__ __forceinline__ unsigned short f2bf(float f) {
  unsigned int u = __builtin_bit_cast(unsigned int, f);
  u += 0x7FFFu + ((u >> 16) & 1u);
  return (unsigned short)(u >> 16);
}

static __device__ __forceinline__ f32x4 mfma_bf16(uint4 a, uint4 b, f32x4 c) {
  return __builtin_amdgcn_mfma_f32_16x16x32_bf16(
      __builtin_bit_cast(bf16x8, a), __builtin_bit_cast(bf16x8, b), c, 0, 0, 0);
}

// ---------------- cast fp32 -> bf16 (8 elems/thread) ----------------
__global__ __launch_bounds__(256) void cast_f32_bf16(
    const float* __restrict__ src, unsigned short* __restrict__ dst, int n8) {
  int i = blockIdx.x * 256 + threadIdx.x;
  if (i >= n8) return;
  const float4* s4 = (const float4*)src;
  float4 a = s4[2*i], b = s4[2*i+1];
  uint4 o;
  o.x = (unsigned)f2bf(a.x) | ((unsigned)f2bf(a.y) << 16);
  o.y = (unsigned)f2bf(a.z) | ((unsigned)f2bf(a.w) << 16);
  o.z = (unsigned)f2bf(b.x) | ((unsigned)f2bf(b.y) << 16);
  o.w = (unsigned)f2bf(b.z) | ((unsigned)f2bf(b.w) << 16);
  ((uint4*)dst)[i] = o;
}

// ---------------- GEMM: C[m][n] = sum_k A[m][k]*B[n][k] + bias[n] ----
// A: M x K bf16 row-major, Bm: N x K bf16 row-major.
// MODE 0: Cf fp32 M x N.  MODE 1: scatter qkv into Qb/Kb/Vb [b][h][s][64] bf16.
template<int MODE>
__global__ __launch_bounds__(256) void gemm_bt(
    const unsigned short* __restrict__ A,
    const unsigned short* __restrict__ Bm,
    const float* __restrict__ bias,
    float* __restrict__ Cf,
    unsigned short* __restrict__ Qb,
    unsigned short* __restrict__ Kb,
    unsigned short* __restrict__ Vb,
    int Ndim, int Kdim)
{
  __shared__ __attribute__((aligned(16))) unsigned short As[128*32];
  __shared__ __attribute__((aligned(16))) unsigned short Bs[128*32];
  const int tid = threadIdx.x;
  const int l = tid & 63, wid = tid >> 6;
  const int g = l >> 4, lr = l & 15;
  const int m0 = blockIdx.y * 128, n0 = blockIdx.x * 128;
  const int wr = (wid >> 1) * 64, wc = (wid & 1) * 64;

  f32x4 acc[4][4] = {};

  // staging: 2 threads/row, 16 elems (2 chunks of 8) each
  const int srow = tid >> 1;
  const int sc0  = (tid & 1) * 16;          // element offset within 32-wide K tile
  const int ch0  = sc0 >> 3;                // chunk index 0 or 2
  const unsigned short* Ag = A + (size_t)(m0 + srow) * Kdim + sc0;
  const unsigned short* Bg = Bm + (size_t)(n0 + srow) * Kdim + sc0;
  const int so0 = srow*32 + ((ch0       ^ (srow & 3)) * 8);
  const int so1 = srow*32 + (((ch0 + 1) ^ (srow & 3)) * 8);

  for (int k0 = 0; k0 < Kdim; k0 += 32) {
    uint4 av0 = *(const uint4*)(Ag + k0);
    uint4 av1 = *(const uint4*)(Ag + k0 + 8);
    uint4 bv0 = *(const uint4*)(Bg + k0);
    uint4 bv1 = *(const uint4*)(Bg + k0 + 8);
    __syncthreads();
    *(uint4*)&As[so0] = av0;  *(uint4*)&As[so1] = av1;
    *(uint4*)&Bs[so0] = bv0;  *(uint4*)&Bs[so1] = bv1;
    __syncthreads();
    uint4 af[4], bf[4];
#pragma unroll
    for (int mi = 0; mi < 4; ++mi)
      af[mi] = *(const uint4*)&As[(wr + mi*16 + lr)*32 + ((g ^ (lr & 3))*8)];
#pragma unroll
    for (int ni = 0; ni < 4; ++ni)
      bf[ni] = *(const uint4*)&Bs[(wc + ni*16 + lr)*32 + ((g ^ (lr & 3))*8)];
#pragma unroll
    for (int mi = 0; mi < 4; ++mi)
#pragma unroll
      for (int ni = 0; ni < 4; ++ni)
        acc[mi][ni] = mfma_bf16(af[mi], bf[ni], acc[mi][ni]);
  }

#pragma unroll
  for (int mi = 0; mi < 4; ++mi)
#pragma unroll
    for (int ni = 0; ni < 4; ++ni)
#pragma unroll
      for (int r = 0; r < 4; ++r) {
        const int row = m0 + wr + mi*16 + g*4 + r;
        const int col = n0 + wc + ni*16 + lr;
        const float v = acc[mi][ni][r] + bias[col];
        if (MODE == 0) {
          Cf[(size_t)row * Ndim + col] = v;
        } else {
          const int h = col / 192, rem = col % 192;
          const int which = rem >> 6, c = rem & 63;
          const int b = row >> 11, s = row & 2047;
          const size_t idx = (((size_t)(b*H_ + h))*S_ + s)*C_ + c;
          unsigned short* dst = (which == 0) ? Qb : (which == 1) ? Kb : Vb;
          dst[idx] = f2bf(v);
        }
      }
}

// ---------------- causal flash attention -----------------------------
// grid: (S/64, B*H), 256 threads (4 waves x 16 q-rows). head dim 64.
__global__ __launch_bounds__(256) void attn_fwd(
    const unsigned short* __restrict__ Qb,
    const unsigned short* __restrict__ Kb,
    const unsigned short* __restrict__ Vb,
    unsigned short* __restrict__ ctx)
{
  __shared__ __attribute__((aligned(16))) unsigned short Ks[32*64];   // [key][c] swizzled
  __shared__ __attribute__((aligned(16))) unsigned short Vt[64*32];   // [d][key] swizzled
  __shared__ __attribute__((aligned(16))) unsigned short Ps[4][16*32];// per-wave P
  const int tid = threadIdx.x, l = tid & 63, wid = tid >> 6;
  const int g = l >> 4, lr = l & 15;
  const int qt = blockIdx.x, bh = blockIdx.y;
  const int qr0 = qt*64 + wid*16;
  const size_t base = (size_t)bh * S_ * C_;
  const float SL = 0.125f * 1.4426950408889634f;   // 1/sqrt(64) * log2(e)

  // Q fragments (2 c-chunks of 32) live in registers for the whole kernel
  uint4 qf[2];
  qf[0] = *(const uint4*)(Qb + base + (size_t)(qr0 + lr)*C_ + g*8);
  qf[1] = *(const uint4*)(Qb + base + (size_t)(qr0 + lr)*C_ + 32 + g*8);

  f32x4 acc[4] = {};
  float mrow[4] = {-1e30f, -1e30f, -1e30f, -1e30f};
  float lsum[4] = {0.f, 0.f, 0.f, 0.f};

  // staging: 8 threads/row, each 8 elems
  const int sr = tid >> 3, sch = tid & 7;
  const int kso = sr*64 + ((sch ^ (sr & 7))*8);
  const int kv_end = qt*64 + 64;

  for (int kv0 = 0; kv0 < kv_end; kv0 += 32) {
    uint4 kvec = *(const uint4*)(Kb + base + (size_t)(kv0 + sr)*C_ + sch*8);
    uint4 vvec = *(const uint4*)(Vb + base + (size_t)(kv0 + sr)*C_ + sch*8);
    __syncthreads();   // previous iteration's LDS reads complete
    *(uint4*)&Ks[kso] = kvec;
    {
      const unsigned short* vv = (const unsigned short*)&vvec;
#pragma unroll
      for (int e = 0; e < 8; ++e) {
        const int d = sch*8 + e;
        Vt[d*32 + (((sr >> 3) ^ (d & 3))*8) + (sr & 7)] = vv[e];
      }
    }
    __syncthreads();
    if (kv0 > qr0 + 15) continue;   // fully masked for this wave

    // QK^T : S tile 16 q-rows x 32 keys
    f32x4 s0 = {}, s1 = {};
#pragma unroll
    for (int ch = 0; ch < 2; ++ch) {
      uint4 k0f = *(const uint4*)&Ks[lr*64      + (((ch*4 + g) ^ (lr & 7))*8)];
      uint4 k1f = *(const uint4*)&Ks[(16+lr)*64 + (((ch*4 + g) ^ (lr & 7))*8)];
      s0 = mfma_bf16(qf[ch], k0f, s0);
      s1 = mfma_bf16(qf[ch], k1f, s1);
    }

    // online softmax (per-16-lane-group, rows g*4+r)
    float p0[4], p1[4], fsc[4];
#pragma unroll
    for (int r = 0; r < 4; ++r) {
      const int qrow = qr0 + g*4 + r;
      const int key0 = kv0 + lr, key1 = kv0 + 16 + lr;
      const float t0 = (key0 <= qrow) ? s0[r]*SL : -1e30f;
      const float t1 = (key1 <= qrow) ? s1[r]*SL : -1e30f;
      float mx = fmaxf(t0, t1);
      mx = fmaxf(mx, __shfl_xor(mx, 1));
      mx = fmaxf(mx, __shfl_xor(mx, 2));
      mx = fmaxf(mx, __shfl_xor(mx, 4));
      mx = fmaxf(mx, __shfl_xor(mx, 8));
      const float mnew = fmaxf(mrow[r], mx);
      const float f = exp2f(mrow[r] - mnew);
      mrow[r] = mnew;
      const float e0 = (key0 <= qrow) ? exp2f(t0 - mnew) : 0.f;
      const float e1 = (key1 <= qrow) ? exp2f(t1 - mnew) : 0.f;
      float ps = e0 + e1;
      ps += __shfl_xor(ps, 1);
      ps += __shfl_xor(ps, 2);
      ps += __shfl_xor(ps, 4);
      ps += __shfl_xor(ps, 8);
      lsum[r] = lsum[r]*f + ps;
      fsc[r] = f;  p0[r] = e0;  p1[r] = e1;
    }
#pragma unroll
    for (int dg = 0; dg < 4; ++dg)
#pragma unroll
      for (int r = 0; r < 4; ++r) acc[dg][r] *= fsc[r];

    // P -> per-wave LDS (transpose C-layout -> A-layout), bf16
    unsigned short* Pw = Ps[wid];
#pragma unroll
    for (int r = 0; r < 4; ++r) {
      const int row = g*4 + r;
      Pw[row*32 + (((lr >> 3)        ^ (row & 3))*8) + (lr & 7)] = f2bf(p0[r]);
      Pw[row*32 + ((((16+lr) >> 3)   ^ (row & 3))*8) + (lr & 7)] = f2bf(p1[r]);
    }
    // PV (same wave: compiler inserts lgkmcnt waits for the LDS dependency)
    const uint4 pa = *(const uint4*)&Pw[lr*32 + ((g ^ (lr & 3))*8)];
#pragma unroll
    for (int dg = 0; dg < 4; ++dg) {
      const int d = dg*16 + lr;
      const uint4 vbf = *(const uint4*)&Vt[d*32 + ((g ^ (d & 3))*8)];
      acc[dg] = mfma_bf16(pa, vbf, acc[dg]);
    }
  }

  // epilogue: normalize, store ctx bf16 [b*S+s][h*64+d]
  const int b = bh >> 4, h = bh & 15;
#pragma unroll
  for (int dg = 0; dg < 4; ++dg)
#pragma unroll
    for (int r = 0; r < 4; ++r) {
      const int qrow = qr0 + g*4 + r;
      const float v = acc[dg][r] / lsum[r];
      ctx[((size_t)(b*S_ + qrow))*D_ + h*C_ + dg*16 + lr] = f2bf(v);
    }
}

// ---------------- launch ---------------------------------------------
extern "C" void kernel_launch(void* const* d_in, const int* in_sizes, int n_in,
                              void* d_out, int out_size, void* d_ws, size_t ws_size,
                              hipStream_t stream) {
  const float* x    = (const float*)d_in[0];
  const float* Wqkv = (const float*)d_in[1];
  const float* bqkv = (const float*)d_in[2];
  const float* Wout = (const float*)d_in[3];
  const float* bout = (const float*)d_in[4];
  float* out = (float*)d_out;

  unsigned short* ws = (unsigned short*)d_ws;
  unsigned short* xb    = ws;
  unsigned short* wqkvb = xb    + (size_t)M_ * D_;        // 4,194,304
  unsigned short* woutb = wqkvb + (size_t)N1_ * D_;       // +3,145,728
  unsigned short* Qb    = woutb + (size_t)D_ * D_;        // +1,048,576
  unsigned short* Kb    = Qb    + (size_t)B_*H_*S_*C_;    // +4,194,304
  unsigned short* Vb    = Kb    + (size_t)B_*H_*S_*C_;
  unsigned short* ctxb  = Vb    + (size_t)B_*H_*S_*C_;

  {
    int n8 = M_*D_/8;
    cast_f32_bf16<<<dim3((n8+255)/256), dim3(256), 0, stream>>>(x, xb, n8);
  }
  {
    int n8 = N1_*D_/8;
    cast_f32_bf16<<<dim3((n8+255)/256), dim3(256), 0, stream>>>(Wqkv, wqkvb, n8);
  }
  {
    int n8 = D_*D_/8;
    cast_f32_bf16<<<dim3((n8+255)/256), dim3(256), 0, stream>>>(Wout, woutb, n8);
  }

  gemm_bt<1><<<dim3(N1_/128, M_/128), dim3(256), 0, stream>>>(
      xb, wqkvb, bqkv, nullptr, Qb, Kb, Vb, N1_, D_);

  attn_fwd<<<dim3(S_/64, B_*H_), dim3(256), 0, stream>>>(Qb, Kb, Vb, ctxb);

  gemm_bt<0><<<dim3(D_/128, M_/128), dim3(256), 0, stream>>>(
      ctxb, woutb, bout, out, nullptr, nullptr, nullptr, D_, D_);
}

// Round 4
// 151.526 us; speedup vs baseline: 1.9494x; 1.9494x over previous
//
#include <hip/hip_runtime.h>
#include <stdint.h>

#define B_ 2
#define S_ 2048
#define D_ 1024
#define H_ 16
#define C_ 64
#define M_ (B_*S_)     // 4096 tokens
#define N1_ (3*D_)     // 3072 qkv cols

typedef float f32x4 __attribute__((ext_vector_type(4)));
typedef float f32x16 __attribute__((ext_vector_type(16)));
typedef __bf16 bf16x8 __attribute__((ext_vector_type(8)));

#define QSCALE 0.18033688f   /* 1/sqrt(64) * log2(e), folded into Q */

static __device__ __forceinline__ unsigned short f2bf(float f) {
  unsigned int u = __builtin_bit_cast(unsigned int, f);
  u += 0x7FFFu + ((u >> 16) & 1u);
  return (unsigned short)(u >> 16);
}

static __device__ __forceinline__ f32x4 mfma_bf16(uint4 a, uint4 b, f32x4 c) {
  return __builtin_amdgcn_mfma_f32_16x16x32_bf16(
      __builtin_bit_cast(bf16x8, a), __builtin_bit_cast(bf16x8, b), c, 0, 0, 0);
}
static __device__ __forceinline__ f32x16 mfma32(uint4 a, uint4 b, f32x16 c) {
  return __builtin_amdgcn_mfma_f32_32x32x16_bf16(
      __builtin_bit_cast(bf16x8, a), __builtin_bit_cast(bf16x8, b), c, 0, 0, 0);
}

// cross-half combine via shfl (known-correct HIP semantics on wave64)
static __device__ __forceinline__ float xmax32(float x) {
  return fmaxf(x, __shfl_xor(x, 32));
}
static __device__ __forceinline__ float xsum32(float x) {
  return x + __shfl_xor(x, 32);
}

// ---------------- cast fp32 -> bf16 (8 elems/thread) ----------------
__global__ __launch_bounds__(256) void cast_f32_bf16(
    const float* __restrict__ src, unsigned short* __restrict__ dst, int n8) {
  int i = blockIdx.x * 256 + threadIdx.x;
  if (i >= n8) return;
  const float4* s4 = (const float4*)src;
  float4 a = s4[2*i], b = s4[2*i+1];
  uint4 o;
  o.x = (unsigned)f2bf(a.x) | ((unsigned)f2bf(a.y) << 16);
  o.y = (unsigned)f2bf(a.z) | ((unsigned)f2bf(a.w) << 16);
  o.z = (unsigned)f2bf(b.x) | ((unsigned)f2bf(b.y) << 16);
  o.w = (unsigned)f2bf(b.z) | ((unsigned)f2bf(b.w) << 16);
  ((uint4*)dst)[i] = o;
}

// ---------------- GEMM: C[m][n] = sum_k A[m][k]*B[n][k] + bias[n] ----
// MODE 0: Cf fp32.  MODE 1: scatter to Qg/Kg [b][h][s][64] (Q pre-scaled) and
//                   Vtg [b][h][d][s] (transposed, ushort4-packed along s).
template<int MODE>
__global__ __launch_bounds__(256) void gemm_bt(
    const unsigned short* __restrict__ A,
    const unsigned short* __restrict__ Bm,
    const float* __restrict__ bias,
    float* __restrict__ Cf,
    unsigned short* __restrict__ Qg,
    unsigned short* __restrict__ Kg,
    unsigned short* __restrict__ Vtg,
    int Ndim, int Kdim)
{
  __shared__ __attribute__((aligned(16))) unsigned short As[128*32];
  __shared__ __attribute__((aligned(16))) unsigned short Bs[128*32];
  const int tid = threadIdx.x;
  const int l = tid & 63, wid = tid >> 6;
  const int g = l >> 4, lr = l & 15;
  const int m0 = blockIdx.y * 128, n0 = blockIdx.x * 128;
  const int wr = (wid >> 1) * 64, wc = (wid & 1) * 64;

  f32x4 acc[4][4] = {};

  const int srow = tid >> 1;
  const int sc0  = (tid & 1) * 16;
  const int ch0  = sc0 >> 3;
  const unsigned short* Ag = A + (size_t)(m0 + srow) * Kdim + sc0;
  const unsigned short* Bg = Bm + (size_t)(n0 + srow) * Kdim + sc0;
  const int so0 = srow*32 + ((ch0       ^ (srow & 3)) * 8);
  const int so1 = srow*32 + (((ch0 + 1) ^ (srow & 3)) * 8);

  for (int k0 = 0; k0 < Kdim; k0 += 32) {
    uint4 av0 = *(const uint4*)(Ag + k0);
    uint4 av1 = *(const uint4*)(Ag + k0 + 8);
    uint4 bv0 = *(const uint4*)(Bg + k0);
    uint4 bv1 = *(const uint4*)(Bg + k0 + 8);
    __syncthreads();
    *(uint4*)&As[so0] = av0;  *(uint4*)&As[so1] = av1;
    *(uint4*)&Bs[so0] = bv0;  *(uint4*)&Bs[so1] = bv1;
    __syncthreads();
    uint4 af[4], bf[4];
#pragma unroll
    for (int mi = 0; mi < 4; ++mi)
      af[mi] = *(const uint4*)&As[(wr + mi*16 + lr)*32 + ((g ^ (lr & 3))*8)];
#pragma unroll
    for (int ni = 0; ni < 4; ++ni)
      bf[ni] = *(const uint4*)&Bs[(wc + ni*16 + lr)*32 + ((g ^ (lr & 3))*8)];
#pragma unroll
    for (int mi = 0; mi < 4; ++mi)
#pragma unroll
      for (int ni = 0; ni < 4; ++ni)
        acc[mi][ni] = mfma_bf16(af[mi], bf[ni], acc[mi][ni]);
  }

#pragma unroll
  for (int mi = 0; mi < 4; ++mi)
#pragma unroll
    for (int ni = 0; ni < 4; ++ni) {
      if (MODE == 0) {
#pragma unroll
        for (int r = 0; r < 4; ++r) {
          const int row = m0 + wr + mi*16 + g*4 + r;
          const int col = n0 + wc + ni*16 + lr;
          Cf[(size_t)row * Ndim + col] = acc[mi][ni][r] + bias[col];
        }
      } else {
        const int colbase = n0 + wc + ni*16;         // multiple of 16
        const int h     = colbase / 192;             // uniform over the 16 lanes
        const int rem   = colbase % 192;
        const int which = rem >> 6;                  // 0=Q 1=K 2=V, uniform
        const int c     = (rem & 63) + lr;
        const float bv  = bias[colbase + lr];
        const int row0  = m0 + wr + mi*16 + g*4;     // 4 consecutive rows
        const int b     = row0 >> 11, s0 = row0 & 2047;
        if (which == 2) {
          ushort4 pk;
          pk.x = f2bf(acc[mi][ni][0] + bv);
          pk.y = f2bf(acc[mi][ni][1] + bv);
          pk.z = f2bf(acc[mi][ni][2] + bv);
          pk.w = f2bf(acc[mi][ni][3] + bv);
          *(ushort4*)(Vtg + ((size_t)(b*H_ + h)*C_ + c)*S_ + s0) = pk;
        } else {
          unsigned short* dst = (which == 0) ? Qg : Kg;
          const float scl = (which == 0) ? QSCALE : 1.0f;
#pragma unroll
          for (int r = 0; r < 4; ++r) {
            const float v = (acc[mi][ni][r] + bv) * scl;
            dst[((size_t)(b*H_ + h)*S_ + (s0 + r))*C_ + c] = f2bf(v);
          }
        }
      }
    }
}

// ---------------- causal flash attention, 32x32 swapped-operand -------
// grid: (bh=32, tilegroup=16), 256 threads = 4 waves x 32 q-rows = 128 rows.
// Q pre-scaled by QSCALE; Vt is [b][h][d][s].
// P transpose goes through per-wave padded LDS (verified-layout path).
#define PS_ 72   /* Pw row stride in elements; 144B = multiple of 16 */
__global__ __launch_bounds__(256) void attn_fwd(
    const unsigned short* __restrict__ Qg,
    const unsigned short* __restrict__ Kg,
    const unsigned short* __restrict__ Vt,
    unsigned short* __restrict__ ctx)
{
  __shared__ __attribute__((aligned(16))) unsigned short sm[8192]; // K[64][64] + V[64][64], swizzled
  __shared__ __attribute__((aligned(16))) unsigned short Ps[4][32*PS_];
  unsigned short* Ks = sm;
  unsigned short* Vs = sm + 4096;

  const int tid = threadIdx.x, l = tid & 63, w = tid >> 6;
  const int ql = l & 31, hi = l >> 5;
  const int bh = blockIdx.x;
  const int tile = 15 - (int)blockIdx.y;        // heavy tiles dispatched first
  const int q0 = tile * 128;
  const int qw0 = q0 + w * 32;
  const int qg = qw0 + ql;
  const size_t baseK = (size_t)bh * S_ * C_;
  const size_t baseV = (size_t)bh * C_ * S_;

  // Q fragments: B-operand, 4 k-chunks of 16 (C=64)
  uint4 qreg[4];
  {
    const unsigned short* qp = Qg + baseK + (size_t)qg * C_ + hi * 8;
#pragma unroll
    for (int kc = 0; kc < 4; ++kc) qreg[kc] = *(const uint4*)(qp + 16*kc);
  }

  f32x16 acc0 = {}, acc1 = {};
  float mrun = -1e30f, lsum = 0.f;

  // staging: thread t covers rows (t>>3, t>>3+32), chunk t&7 of both tiles
  const int srow = tid >> 3, sch = tid & 7;
  const unsigned short* Kgp = Kg + baseK + (size_t)srow * C_ + sch * 8;
  const unsigned short* Vgp = Vt + baseV + (size_t)srow * S_ + sch * 8;
  const int kwo = srow*64 + ((sch ^ (srow & 7))*8);        // swizzled write (row srow)
  const int kwo2 = (srow+32)*64 + ((sch ^ (srow & 7))*8);  // (srow+32)&7 == srow&7
  const int kv_end = q0 + 128;

  uint4 kp0 = *(const uint4*)(Kgp);
  uint4 kp1 = *(const uint4*)(Kgp + 32*C_);
  uint4 vp0 = *(const uint4*)(Vgp);
  uint4 vp1 = *(const uint4*)(Vgp + 32*(size_t)S_);

  for (int kv0 = 0; kv0 < kv_end; kv0 += 64) {
    __syncthreads();                       // all waves done reading previous tile
    *(uint4*)&Ks[kwo]  = kp0;  *(uint4*)&Ks[kwo2] = kp1;
    *(uint4*)&Vs[kwo]  = vp0;  *(uint4*)&Vs[kwo2] = vp1;
    __syncthreads();                       // tile visible
    if (kv0 + 64 < kv_end) {               // prefetch next tile (hides under compute)
      kp0 = *(const uint4*)(Kgp + (size_t)(kv0+64)*C_);
      kp1 = *(const uint4*)(Kgp + (size_t)(kv0+64)*C_ + 32*C_);
      vp0 = *(const uint4*)(Vgp + (kv0+64));
      vp1 = *(const uint4*)(Vgp + (kv0+64) + 32*(size_t)S_);
    }
    if (kv0 > qw0 + 31) continue;          // fully masked for this wave (uniform)

    // ---- QK^T: St[key][q], two 32-key blocks ----
    f32x16 st0 = {}, st1 = {};
    __builtin_amdgcn_s_setprio(1);
#pragma unroll
    for (int kc = 0; kc < 4; ++kc) {
      const int pc = (hi + 2*kc);
      uint4 k0 = *(const uint4*)&Ks[(ql)*64      + ((pc ^ (ql & 7))*8)];
      uint4 k1 = *(const uint4*)&Ks[(32+ql)*64   + ((pc ^ (ql & 7))*8)];
      st0 = mfma32(k0, qreg[kc], st0);
      st1 = mfma32(k1, qreg[kc], st1);
    }
    __builtin_amdgcn_s_setprio(0);

    // ---- mask (diagonal tiles only) ----
    if (kv0 + 63 > qw0) {
#pragma unroll
      for (int r = 0; r < 16; ++r) {
        const int krow = (r & 3) + 8*(r >> 2) + 4*hi;
        if (kv0 + krow      > qg) st0[r] = -1e30f;
        if (kv0 + 32 + krow > qg) st1[r] = -1e30f;
      }
    }

    // ---- online softmax, fully in-register ----
    float mt = -1e30f;
#pragma unroll
    for (int r = 0; r < 16; ++r) { mt = fmaxf(mt, st0[r]); mt = fmaxf(mt, st1[r]); }
    mt = xmax32(mt);
    const float mnew = fmaxf(mrun, mt);
    const float fr = exp2f(mrun - mnew);
    mrun = mnew;
    float psum = 0.f;
#pragma unroll
    for (int r = 0; r < 16; ++r) {
      st0[r] = exp2f(st0[r] - mnew); psum += st0[r];
      st1[r] = exp2f(st1[r] - mnew); psum += st1[r];
    }
    lsum = lsum * fr + psum;
#pragma unroll
    for (int r = 0; r < 16; ++r) { acc0[r] *= fr; acc1[r] *= fr; }

    // ---- P -> per-wave LDS Pw[q][key] (pair-packed), then B-fragments ----
    // st regs r (even), r+1 map to keys crow(r), crow(r)+1 (verified C-layout).
    unsigned short* Pw = Ps[w];
#pragma unroll
    for (int r = 0; r < 16; r += 2) {
      const int key = (r & 3) + 8*(r >> 2) + 4*hi;   // even
      const unsigned d0 = (unsigned)f2bf(st0[r]) | ((unsigned)f2bf(st0[r+1]) << 16);
      const unsigned d1 = (unsigned)f2bf(st1[r]) | ((unsigned)f2bf(st1[r+1]) << 16);
      *(unsigned*)&Pw[ql*PS_ + key]      = d0;
      *(unsigned*)&Pw[ql*PS_ + 32 + key] = d1;
    }
    // B-frag slot (j,hi) of chunk kc needs P[key=16kc+8hi+j][q=ql]
    uint4 pb[4];
#pragma unroll
    for (int kc = 0; kc < 4; ++kc)
      pb[kc] = *(const uint4*)&Pw[ql*PS_ + kc*16 + hi*8];

    // ---- PV: accT[d][q] += Vt_frag x P_frag ----
    __builtin_amdgcn_s_setprio(1);
#pragma unroll
    for (int kc = 0; kc < 4; ++kc) {
      const int pc = (hi + 2*kc);
      uint4 v0 = *(const uint4*)&Vs[(ql)*64    + ((pc ^ (ql & 7))*8)];
      uint4 v1 = *(const uint4*)&Vs[(32+ql)*64 + ((pc ^ (ql & 7))*8)];
      acc0 = mfma32(v0, pb[kc], acc0);
      acc1 = mfma32(v1, pb[kc], acc1);
    }
    __builtin_amdgcn_s_setprio(0);
  }

  // ---- epilogue: normalize, LDS transpose, coalesced store ----
  __syncthreads();                          // everyone done with K/V tiles
  const float inv = 1.0f / xsum32(lsum);
  unsigned short* E = sm + w * 2048;        // per-wave 32q x 64d region
#pragma unroll
  for (int r = 0; r < 16; ++r) {
    const int d0 = (r & 3) + 8*(r >> 2) + 4*hi;
    E[ql*64 + ( d0        ^ (8*(ql & 7)))] = f2bf(acc0[r] * inv);
    E[ql*64 + ((32 + d0)  ^ (8*(ql & 7)))] = f2bf(acc1[r] * inv);
  }
  // read back rows, vector-store to ctx [token][1024]
  const int q1 = l >> 1, half = l & 1;
  const unsigned short* Er = E + q1*64;
  const int b = bh >> 4, h = bh & 15;
  unsigned short* outp = ctx + ((size_t)(b*S_ + q0 + w*32 + q1))*D_ + h*C_;
#pragma unroll
  for (int j = 0; j < 4; ++j) {
    const int clog = half*4 + j;
    const int cx = clog ^ (q1 & 7);
    uint4 val = *(const uint4*)&Er[cx*8];
    *(uint4*)(outp + clog*8) = val;
  }
}

// ---------------- launch ---------------------------------------------
extern "C" void kernel_launch(void* const* d_in, const int* in_sizes, int n_in,
                              void* d_out, int out_size, void* d_ws, size_t ws_size,
                              hipStream_t stream) {
  const float* x    = (const float*)d_in[0];
  const float* Wqkv = (const float*)d_in[1];
  const float* bqkv = (const float*)d_in[2];
  const float* Wout = (const float*)d_in[3];
  const float* bout = (const float*)d_in[4];
  float* out = (float*)d_out;

  unsigned short* ws = (unsigned short*)d_ws;
  unsigned short* xb    = ws;
  unsigned short* wqkvb = xb    + (size_t)M_ * D_;
  unsigned short* woutb = wqkvb + (size_t)N1_ * D_;
  unsigned short* Qb    = woutb + (size_t)D_ * D_;
  unsigned short* Kb    = Qb    + (size_t)B_*H_*S_*C_;
  unsigned short* Vtb   = Kb    + (size_t)B_*H_*S_*C_;
  unsigned short* ctxb  = Vtb   + (size_t)B_*H_*S_*C_;

  {
    int n8 = M_*D_/8;
    cast_f32_bf16<<<dim3((n8+255)/256), dim3(256), 0, stream>>>(x, xb, n8);
  }
  {
    int n8 = N1_*D_/8;
    cast_f32_bf16<<<dim3((n8+255)/256), dim3(256), 0, stream>>>(Wqkv, wqkvb, n8);
  }
  {
    int n8 = D_*D_/8;
    cast_f32_bf16<<<dim3((n8+255)/256), dim3(256), 0, stream>>>(Wout, woutb, n8);
  }

  gemm_bt<1><<<dim3(N1_/128, M_/128), dim3(256), 0, stream>>>(
      xb, wqkvb, bqkv, nullptr, Qb, Kb, Vtb, N1_, D_);

  attn_fwd<<<dim3(32, 16), dim3(256), 0, stream>>>(Qb, Kb, Vtb, ctxb);

  gemm_bt<0><<<dim3(D_/128, M_/128), dim3(256), 0, stream>>>(
      ctxb, woutb, bout, out, nullptr, nullptr, nullptr, D_, D_);
}